// Round 9
// baseline (190.737 us; speedup 1.0000x reference)
//
#include <hip/hip_runtime.h>
#include <hip/hip_bf16.h>
#include <math.h>

typedef unsigned short ushort_t;
typedef unsigned int   u32;
typedef __attribute__((ext_vector_type(8))) short s8v;
typedef __attribute__((ext_vector_type(4))) float f4v;
typedef __attribute__((ext_vector_type(2))) float f2v;

#define LL 64
#define NB 64
#define NSITE 4096
#define BN 262144
#define RED_OFF 0         // [0,10240): per-block red partials, blk*10+n
#define WA_OFF  11264
#define WB_OFF  11392
#define PL_OFF  12288     // planes: h, RA, RB, TAa, TAb, TBb (6*BN floats)
#define BF_OFF  (PL_OFF + 6*BN)   // 2048 s8v (bf16-rne W2 fragments)

#if __has_builtin(__builtin_amdgcn_exp2f)
#define EXP2F(x) __builtin_amdgcn_exp2f(x)
#else
#define EXP2F(x) __expf(0.6931471805599453f*(x))
#endif

// fast exact-GELU: value + 1st/2nd derivative. erf via A&S 7.1.26 (|eps|<=1.5e-7)
__device__ __forceinline__ void gelu3(float u, float &h, float &d, float &e){
  float E   = __expf(-0.5f * u * u);
  float phi = 0.3989422804014327f * E;
  float az  = fabsf(u) * 0.70710678118654752f;
  float t   = __builtin_amdgcn_rcpf(1.0f + 0.3275911f * az);
  float p   = t*(0.254829592f + t*(-0.284496736f + t*(1.421413741f + t*(-1.453152027f + t*1.061405429f))));
  float erfabs = 1.0f - p * E;
  float erfv   = __builtin_copysignf(erfabs, u);
  float Phi = 0.5f * (1.0f + erfv);
  h = u * Phi;
  d = Phi + u * phi;
  e = phi * (2.0f - u * u);
}

// packed-pair exact GELU (v_pk_* f32 path): same constants as gelu3
__device__ __forceinline__ void gelu3x2(f2v u, f2v &h, f2v &d, f2v &e){
  f2v u2 = u * u;
  f2v m  = u2 * (-0.72134752044448170368f);   // -0.5*log2(e)
  f2v E;  E.x = EXP2F(m.x); E.y = EXP2F(m.y);
  f2v phi = 0.3989422804014327f * E;
  f2v az;
  az.x = fabsf(u.x) * 0.70710678118654752f;
  az.y = fabsf(u.y) * 0.70710678118654752f;
  f2v den = 0.3275911f * az + 1.0f;
  f2v t;  t.x = __builtin_amdgcn_rcpf(den.x); t.y = __builtin_amdgcn_rcpf(den.y);
  f2v p = t*(0.254829592f + t*(-0.284496736f + t*(1.421413741f + t*(-1.453152027f + t*1.061405429f))));
  f2v erfabs = 1.0f - p * E;
  f2v erfv;
  erfv.x = __builtin_copysignf(erfabs.x, u.x);
  erfv.y = __builtin_copysignf(erfabs.y, u.y);
  f2v Phi = 0.5f * erfv + 0.5f;
  h = u * Phi;
  d = u * phi + Phi;
  e = phi * (2.0f - u2);
}

// 16-lane row reduction entirely in the VALU pipe (DPP), no LDS ops.
#define DPP_ADD(v, ctrl) { \
  int _si = __builtin_amdgcn_update_dpp(0, __builtin_bit_cast(int, v), ctrl, 0xf, 0xf, true); \
  v += __builtin_bit_cast(float, _si); }

__device__ __forceinline__ float redjb16(float v){
  DPP_ADD(v, 0xB1);
  DPP_ADD(v, 0x4E);
  DPP_ADD(v, 0x124);
  DPP_ADD(v, 0x128);
  return v;
}
// 64-lane reduction: 4 DPP stages within rows + 2 cross-row shuffles
__device__ __forceinline__ float red64(float v){
  v = redjb16(v);
  v += __shfl_xor(v, 16);
  v += __shfl_xor(v, 32);
  return v;
}

__device__ __forceinline__ ushort_t bf16rne(float v){
  union { float f; u32 i; } x; x.f = v;
  u32 r = x.i + 0x7FFFu + ((x.i >> 16) & 1u);
  return (ushort_t)(r >> 16);
}
// packed rne bf16 of two floats -> u32 (low = a, high = b); lowers to v_cvt_pk_bf16_f32
__device__ __forceinline__ u32 pkbf(float a, float b){
  __hip_bfloat162 t = __float22bfloat162_rn(make_float2(a, b));
  u32 r;
  __builtin_memcpy(&r, &t, sizeof(r));
  return r;
}
__device__ __forceinline__ u32 pkbf2(f2v v){
  return pkbf(v.x, v.y);
}

// ---------------- one-time prep: wa/wb + W2 rne-bf16 fragments + lapl-slot zeroing ----------------
__global__ __launch_bounds__(256, 4) void k_pre(
    const float* __restrict__ W1g, const float* __restrict__ W2g,
    float* __restrict__ ws, float* __restrict__ out)
{
  int t = blockIdx.x * 256 + threadIdx.x;     // 0..2047
  if (blockIdx.x == 0 && threadIdx.x < 128) {
    int k = threadIdx.x;
    ws[WA_OFF + k] = W1g[k] + W1g[256+k] + W1g[384+k];
    ws[WB_OFF + k] = W1g[128+k];
  }
  if (blockIdx.x == 1 && threadIdx.x < 64) {
    out[(size_t)threadIdx.x*4097 + 4096] = 0.f;   // lapl accumulators (k_c2 atomicAdds)
  }
  short* BF = (short*)(ws + BF_OFF);
  int w = t >> 9, nt = (t >> 8) & 1, kt = (t >> 6) & 3, lane = t & 63;
  int q = lane >> 4, nlo = lane & 15;
  int n = w*32 + nt*16 + nlo;
  s8v vh;
  #pragma unroll
  for (int jj = 0; jj < 8; ++jj) {
    int k = kt*32 + q*8 + jj;
    vh[jj] = (short)bf16rne(W2g[k*128 + n]);
  }
  *(s8v*)&BF[t*8] = vh;
}

// ---------------- heavy kernel: one (batch, 4-row group), 16 chunks of 16 sites ----------------
// grid 1024 = 64 b * 16 row-groups ; block 256 (4 waves); 4 blocks/CU
// r8 winner + kt0/kt1 B-loads issued BEFORE the P1 barrier (L2 latency hidden under P1).
__global__ __launch_bounds__(256, 4) void k_c1(
    const float* __restrict__ xg, const int* __restrict__ signs,
    const float* __restrict__ b1g, const float* __restrict__ b2g,
    const float* __restrict__ W3g, const float* __restrict__ b3g,
    float* __restrict__ ws)
{
  // AF: [kt(4)][plane(6)] x 512 shorts ; planes: {h, d*wa, d*wb, e*waa, e*wab, e*wbb}
  __shared__ alignas(16) short AF[12288];     // 24 KB
  __shared__ float xS[6][64];                 // rows i0-1..i0+4  (1.5 KB)
  __shared__ char  zS[6][64];                 // signs as +-1     (384 B)
  __shared__ float EP[16][7][4];              // padded stride (1.75 KB)

  const int tid  = threadIdx.x;
  const int lane = tid & 63;
  const int w    = tid >> 6;
  const int rg4  = (lane >> 4) << 2;          // n-quad base within a 16-n block

  const int blk = blockIdx.x;
  const int b   = blk >> 4;
  const int i0  = (blk & 15) << 2;            // first of four rows

  // per-thread B-fragment pointer (L2-resident pre-rounded W2), streamed with prefetch
  const s8v* BhT = (const s8v*)((const short*)(ws + BF_OFF)) + (w*512 + lane);

  // per-lane n-quad biases/weights for the transposed epilogue (n = w*32 + nt*16 + rg4 + r)
  float4 b2H[2], w3H[2];
  #pragma unroll
  for (int nt = 0; nt < 2; ++nt) {
    int n0 = w*32 + nt*16 + rg4;
    b2H[nt] = *(const float4*)(b2g + n0);
    w3H[nt] = *(const float4*)(W3g + n0);
  }
  float b3v = b3g[0];

  // P1 thread geometry + loop-invariant layer-1 weights/bias (hoisted)
  const int s_  = tid & 15;
  const int ko_ = tid >> 4;
  float4 waH[2], wbH[2], b1H[2];
  #pragma unroll
  for (int half = 0; half < 2; ++half) {
    int k0 = ko_*8 + half*4;
    waH[half] = *(const float4*)(ws + WA_OFF + k0);
    wbH[half] = *(const float4*)(ws + WB_OFF + k0);
    b1H[half] = *(const float4*)(b1g + k0);
  }

  // ---- stage 6 x-rows and 6 sign-rows ----
  for (int t = tid; t < 384; t += 256) {
    int r = t >> 6, j = t & 63;
    int gr = (i0 - 1 + r) & 63;
    xS[r][j] = xg[(size_t)b*NSITE + gr*64 + j];
    int c = ((gr & 1) << 1) | (j & 1);
    zS[r][j] = (char)(2*signs[((c*NB + b)*LL + gr)*LL + j] - 1);
  }
  __syncthreads();

  float racc[10];
  #pragma unroll
  for (int n = 0; n < 10; ++n) racc[n] = 0.f;

  const f4v Zf = {0.f, 0.f, 0.f, 0.f};        // hoisted zero C-operand

  #pragma unroll 1
  for (int ch = 0; ch < 16; ++ch) {
    const int lr = 1 + (ch >> 2);             // local row 1..4
    const int jb = ch & 3;
    const int i  = i0 + (ch >> 2);

    // ---- issue kt0/kt1 B loads early: latency hides under P1 compute ----
    s8v pb00 = BhT[0],  pb10 = BhT[256];
    s8v pb01 = BhT[64], pb11 = BhT[320];

    // ---- P1: build A fragments (packed-pair math, single b128 write per plane) ----
    {
      int j = jb*16 + s_, jm = (j+63)&63, jp = (j+1)&63;
      float p = xS[lr][j];
      float l = xS[lr-1][j] + xS[lr+1][j] + xS[lr][jm] + xS[lr][jp] - 4.0f*p;
      u32 vv[6][4];                           // [plane][half*2+pr]
      #pragma unroll
      for (int half = 0; half < 2; ++half) {
        const float* waA = (const float*)&waH[half];
        const float* wbA = (const float*)&wbH[half];
        const float* b1A = (const float*)&b1H[half];
        #pragma unroll
        for (int pr = 0; pr < 2; ++pr) {
          f2v wa = {waA[pr*2], waA[pr*2+1]};
          f2v wb = {wbA[pr*2], wbA[pr*2+1]};
          f2v bb = {b1A[pr*2], b1A[pr*2+1]};
          f2v u = p*wa + l*wb + bb;
          f2v h, dd, ee;
          gelu3x2(u, h, dd, ee);
          int c = half*2 + pr;
          vv[0][c] = pkbf2(h);
          vv[1][c] = pkbf2(dd*wa);
          vv[2][c] = pkbf2(dd*wb);
          f2v ea = ee*wa, eb = ee*wb;
          vv[3][c] = pkbf2(ea*wa);
          vv[4][c] = pkbf2(ea*wb);
          vv[5][c] = pkbf2(eb*wb);
        }
      }
      // one conflict-free ds_write_b128 per plane (per-wave addr == lane*16 + const)
      short* base = &AF[(ko_>>2)*3072 + ((ko_&3)*16 + s_)*8];
      #pragma unroll
      for (int pp = 0; pp < 6; ++pp)
        *(int4*)&base[pp*512] = make_int4((int)vv[pp][0], (int)vv[pp][1],
                                          (int)vv[pp][2], (int)vv[pp][3]);
    }
    __syncthreads();

    // ---- P2: transposed MFMA (B as a-operand), kt=0 peeled with zero C ----
    f4v acc[6][2];
    __builtin_amdgcn_s_setprio(1);
    {
      const short* base = &AF[lane*8];
      #pragma unroll
      for (int pp = 0; pp < 6; ++pp) {
        s8v ah = *(const s8v*)&base[pp*512];
        acc[pp][0] = __builtin_amdgcn_mfma_f32_16x16x32_bf16(pb00, ah, Zf, 0, 0, 0);
        acc[pp][1] = __builtin_amdgcn_mfma_f32_16x16x32_bf16(pb10, ah, Zf, 0, 0, 0);
      }
    }
    s8v bh0 = pb01, bh1 = pb11;
    #pragma unroll 1
    for (int kt = 1; kt < 4; ++kt) {
      s8v nh0 = bh0, nh1 = bh1;
      if (kt != 3) {
        int o = (kt + 1) * 64;
        nh0 = BhT[o]; nh1 = BhT[256 + o];
      }
      const short* base = &AF[kt*3072 + lane*8];
      #pragma unroll
      for (int pp = 0; pp < 6; ++pp) {
        s8v ah = *(const s8v*)&base[pp*512];
        acc[pp][0] = __builtin_amdgcn_mfma_f32_16x16x32_bf16(bh0, ah, acc[pp][0], 0, 0, 0);
        acc[pp][1] = __builtin_amdgcn_mfma_f32_16x16x32_bf16(bh1, ah, acc[pp][1], 0, 0, 0);
      }
      bh0 = nh0; bh1 = nh1;
    }
    __builtin_amdgcn_s_setprio(0);

    // ---- P3: transposed epilogue — n-sum is per-lane FMA + 2 shfl stages ----
    {
      f2v qh = {0.f,0.f}, qA = {0.f,0.f}, qB = {0.f,0.f};
      f2v qa = {0.f,0.f}, qb = {0.f,0.f}, qc = {0.f,0.f};
      #pragma unroll
      for (int nt = 0; nt < 2; ++nt) {
        const float* b2A = (const float*)&b2H[nt];
        const float* w3A = (const float*)&w3H[nt];
        #pragma unroll
        for (int pr = 0; pr < 2; ++pr) {
          const int r0 = pr*2;
          f2v uu  = (f2v){acc[0][nt][r0], acc[0][nt][r0+1]}
                  + (f2v){b2A[r0], b2A[r0+1]};
          f2v w3p = {w3A[r0], w3A[r0+1]};
          f2v h2, d2, e2;
          gelu3x2(uu, h2, d2, e2);
          f2v wd = w3p*d2, we = w3p*e2;
          f2v A  = {acc[1][nt][r0], acc[1][nt][r0+1]};
          f2v Bv = {acc[2][nt][r0], acc[2][nt][r0+1]};
          f2v t3 = {acc[3][nt][r0], acc[3][nt][r0+1]};
          f2v t4 = {acc[4][nt][r0], acc[4][nt][r0+1]};
          f2v t5 = {acc[5][nt][r0], acc[5][nt][r0+1]};
          qh += w3p*h2;
          qA += wd*A;
          qB += wd*Bv;
          qa += we*(A*A)   + wd*t3;
          qb += we*(A*Bv)  + wd*t4;
          qc += we*(Bv*Bv) + wd*t5;
        }
      }
      float sh = qh.x + qh.y;
      float sA = qA.x + qA.y;
      float sB = qB.x + qB.y;
      float sa = qa.x + qa.y;
      float sb = qb.x + qb.y;
      float sc = qc.x + qc.y;
      sh += __shfl_xor(sh, 16); sh += __shfl_xor(sh, 32);
      sA += __shfl_xor(sA, 16); sA += __shfl_xor(sA, 32);
      sB += __shfl_xor(sB, 16); sB += __shfl_xor(sB, 32);
      sa += __shfl_xor(sa, 16); sa += __shfl_xor(sa, 32);
      sb += __shfl_xor(sb, 16); sb += __shfl_xor(sb, 32);
      sc += __shfl_xor(sc, 16); sc += __shfl_xor(sc, 32);
      if (lane < 16) {
        EP[lane][0][w] = sh;
        EP[lane][1][w] = sA;
        EP[lane][2][w] = sB;
        EP[lane][3][w] = sa;
        EP[lane][4][w] = sb;
        EP[lane][5][w] = sc;
      }
    }
    __syncthreads();

    // ---- P4: per-site finalize + batch accumulation (16 threads; overlaps next P1) ----
    if (tid < 16) {
      int s = tid;
      float h = 0.f, RA = 0.f, RB = 0.f, TAa = 0.f, TAb = 0.f, TBb = 0.f;
      #pragma unroll
      for (int ww = 0; ww < 4; ++ww) {
        h   += EP[s][0][ww];
        RA  += EP[s][1][ww];
        RB  += EP[s][2][ww];
        TAa += EP[s][3][ww];
        TAb += EP[s][4][ww];
        TBb += EP[s][5][ww];
      }
      h += b3v;
      float* P = ws + PL_OFF;
      int j = jb*16 + s;
      size_t site = (size_t)b*NSITE + i*64 + j;
      P[0*BN + site] = h;
      P[1*BN + site] = RA;
      P[2*BN + site] = RB;
      P[3*BN + site] = TAa;
      P[4*BN + site] = TAb;
      P[5*BN + site] = TBb;

      int jm = (j+63)&63, jp = (j+1)&63;
      int c0 = ((i & 1) << 1) | (j & 1);
      float hd[4] = {0.f, 0.f, 0.f, 0.f};
      hd[c0]     = (float)zS[lr][j] * (RA - 4.0f*RB);
      hd[c0 ^ 1] = (float)(zS[lr][jm] + zS[lr][jp]) * RB;
      hd[c0 ^ 2] = (float)(zS[lr-1][j] + zS[lr+1][j]) * RB;
      racc[0] += h;
      racc[1] += h*h;
      #pragma unroll
      for (int cc = 0; cc < 4; ++cc) {
        racc[2+cc] += hd[cc];
        racc[6+cc] += h*hd[cc];
      }
    }
  }

  // ---- final batch reduction: write this block's partials to its private slot ----
  if (tid < 16) {
    #pragma unroll
    for (int n = 0; n < 10; ++n) racc[n] = redjb16(racc[n]);
    if (tid == 0) {
      #pragma unroll
      for (int n = 0; n < 10; ++n) ws[RED_OFF + blk*10 + n] = racc[n];
    }
  }
}

// ---------------- stencil + fused head calculus (atomic lapl tail) ----------------
// (256,4): cap VGPR at 128 — the old (256,1) bound allowed the allocator to
// inflate past 256 VGPRs and collapse occupancy to 1-2 waves/SIMD.
__global__ __launch_bounds__(256, 4) void k_c2(
    const int* __restrict__ signs,
    const float* __restrict__ aW1g, const float* __restrict__ ab1g,
    const float* __restrict__ aW2g,
    float* __restrict__ ws, float* __restrict__ out)
{
  __shared__ float part[4];
  __shared__ float coefL[10];
  __shared__ float redS[10];
  __shared__ float cbS[6][64];
  int blk = blockIdx.x;
  int b = blk >> 4, rg = blk & 15;
  int tid = threadIdx.x;

  // sum the 16 per-block partials for this batch (parallel: 160 threads, DPP rows)
  if (tid < 160) {
    int qq = tid >> 4, g = tid & 15;          // 16-lane DPP row == one quantity
    float v = ws[RED_OFF + (b*16 + g)*10 + qq];
    v = redjb16(v);
    if (g == 0) redS[qq] = v;
  }
  __syncthreads();

  if (tid < 64) {
    int k = tid;
    const float Nf = 4096.0f, Nm1 = 4095.0f;
    float S1 = redS[0], S2 = redS[1];
    float m = S1/Nf, q = S2/Nf;
    float v = (S2 - S1*S1/Nf)/Nm1;
    float w0 = aW1g[k], w1 = aW1g[64+k], w2 = aW1g[128+k];
    float t = m*w0 + v*w1 + q*w2 + ab1g[k];
    float gh, gd, ge;
    gelu3(t, gh, gd, ge);
    float o = aW2g[k];
    float g1o = gd*o, g2o = ge*o;
    float da0 = w0*g1o, da1 = w1*g1o, da2 = w2*g1o;
    float M00 = w0*w0*g2o, M01 = w0*w1*g2o, M02 = w0*w2*g2o;
    float M11 = w1*w1*g2o, M12 = w1*w2*g2o, M22 = w2*w2*g2o;
    da0 = red64(da0); da1 = red64(da1); da2 = red64(da2);
    M00 = red64(M00); M01 = red64(M01); M02 = red64(M02);
    M11 = red64(M11); M12 = red64(M12); M22 = red64(M22);
    if (k == 0) {
      coefL[0] = da0/Nf - 2.0f*da1*m/Nm1;
      coefL[1] = 2.0f*da1/Nm1 + 2.0f*da2/Nf;
      #pragma unroll
      for (int c = 0; c < 4; ++c) {
        float s1 = redS[2 + c], s2 = redS[6 + c];
        float md = s1/Nf, qd = 2.0f*s2/Nf;
        float vd = (2.0f*s2 - 2.0f*S1*s1/Nf)/Nm1;
        float dd0 = M00*md + M01*vd + M02*qd;
        float dd1 = M01*md + M11*vd + M12*qd;
        float dd2 = M02*md + M12*vd + M22*qd;
        coefL[2+c] = dd0/Nf - 2.0f*(dd1*m + da1*md)/Nm1;
        coefL[6+c] = 2.0f*dd1/Nm1 + 2.0f*dd2/Nf;
      }
    }
  }
  __syncthreads();

  const float* P = ws + PL_OFF;
  int base = b*NSITE;
  float alpha = coefL[0], beta = coefL[1];

  // stage cb = (alpha + beta*h) * RB for rows rg*4-1 .. rg*4+4
  for (int t = tid; t < 384; t += 256) {
    int r = t >> 6, jj = t & 63;
    int gr = (rg*4 - 1 + r) & 63;
    int sidx = base + gr*64 + jj;
    cbS[r][jj] = (alpha + beta*P[sidx]) * P[2*BN + sidx];
  }
  __syncthreads();

  int rl = tid >> 6, j = tid & 63;
  int i = rg*4 + rl;
  int im=(i+63)&63, ip=(i+1)&63, jm=(j+63)&63, jp=(j+1)&63;
  int s  = base + i*64 + j;
  float h  = P[s], RA = P[BN+s], RB = P[2*BN+s];
  float TAa= P[3*BN+s], TAb = P[4*BN+s], TBb = P[5*BN+s];
  float g  = alpha + beta*h;
  int lr2 = rl + 1;
  float cb  = cbS[lr2][j];
  float cbu = cbS[lr2-1][j], cbd = cbS[lr2+1][j];
  float cbl = cbS[lr2][jm],  cbr = cbS[lr2][jp];
  float grad = g*RA + (cbu + cbd + cbl + cbr - 4.0f*cb);
  out[(size_t)b*4097 + i*64 + j] = grad;

  int c0 = ((i & 1) << 1) | (j & 1);
  int c1 = c0 ^ 1, c2 = c0 ^ 2;
  float zv = 2.0f*(float)signs[((c0*NB + b)*LL + i )*LL + j ] - 1.0f;
  float zl = 2.0f*(float)signs[((c1*NB + b)*LL + i )*LL + jm] - 1.0f;
  float zr = 2.0f*(float)signs[((c1*NB + b)*LL + i )*LL + jp] - 1.0f;
  float zu = 2.0f*(float)signs[((c2*NB + b)*LL + im)*LL + j ] - 1.0f;
  float zd = 2.0f*(float)signs[((c2*NB + b)*LL + ip)*LL + j ] - 1.0f;
  float sjr = zl + zr, sud = zu + zd;
  float hd0 = zv*(RA - 4.0f*RB);
  float hd1 = sjr*RB, hd2 = sud*RB;
  float gd0 = coefL[2+c0] + coefL[6+c0]*h + beta*hd0;
  float gd1 = coefL[2+c1] + coefL[6+c1]*h + beta*hd1;
  float gd2 = coefL[2+c2] + coefL[6+c2]*h + beta*hd2;
  float ca0 = gd0*RA + g*( zv*TAa - 4.0f*zv*TAb );
  float cb0 = gd0*RB + g*( zv*TAb - 4.0f*zv*TBb );
  float cb1 = gd1*RB + g*( sjr*TBb );
  float cb2 = gd2*RB + g*( sud*TBb );
  float contrib = zv*ca0 - 4.0f*zv*cb0 + sjr*cb1 + sud*cb2;

  float vsum = red64(contrib);
  int wv = tid >> 6;
  if ((tid & 63) == 0) part[wv] = vsum;
  __syncthreads();
  if (tid == 0)
    atomicAdd(out + (size_t)b*4097 + 4096,
              part[0] + part[1] + part[2] + part[3]);
}

extern "C" void kernel_launch(void* const* d_in, const int* in_sizes, int n_in,
                              void* d_out, int out_size, void* d_ws, size_t ws_size,
                              hipStream_t stream) {
  const float* xg    = (const float*)d_in[0];
  const int*   signs = (const int*)d_in[1];
  const float* W1    = (const float*)d_in[2];
  const float* b1    = (const float*)d_in[3];
  const float* W2    = (const float*)d_in[4];
  const float* b2    = (const float*)d_in[5];
  const float* W3    = (const float*)d_in[6];
  const float* b3    = (const float*)d_in[7];
  const float* aW1   = (const float*)d_in[8];
  const float* ab1   = (const float*)d_in[9];
  const float* aW2   = (const float*)d_in[10];
  float* ws  = (float*)d_ws;
  float* out = (float*)d_out;

  hipLaunchKernelGGL(k_pre, dim3(8),    dim3(256), 0, stream, W1, W2, ws, out);
  hipLaunchKernelGGL(k_c1,  dim3(1024), dim3(256), 0, stream,
                     xg, signs, b1, b2, W3, b3, ws);
  hipLaunchKernelGGL(k_c2,  dim3(1024), dim3(256), 0, stream,
                     signs, aW1, ab1, aW2, ws, out);
}

// Round 10
// 188.605 us; speedup vs baseline: 1.0113x; 1.0113x over previous
//
#include <hip/hip_runtime.h>
#include <hip/hip_bf16.h>
#include <math.h>

typedef unsigned short ushort_t;
typedef unsigned int   u32;
typedef __attribute__((ext_vector_type(8))) short s8v;
typedef __attribute__((ext_vector_type(4))) float f4v;
typedef __attribute__((ext_vector_type(2))) float f2v;

#define LL 64
#define NB 64
#define NSITE 4096
#define BN 262144
#define RED_OFF 0         // [0,10240): per-block red partials, blk*10+n
#define WA_OFF  11264
#define WB_OFF  11392
#define PL_OFF  12288     // planes: h, RA, RB, TAa, TAb, TBb (6*BN floats)
#define BF_OFF  (PL_OFF + 6*BN)   // 2048 s8v (bf16-rne W2 fragments)

#if __has_builtin(__builtin_amdgcn_exp2f)
#define EXP2F(x) __builtin_amdgcn_exp2f(x)
#else
#define EXP2F(x) __expf(0.6931471805599453f*(x))
#endif

// fast exact-GELU: value + 1st/2nd derivative. erf via A&S 7.1.26 (|eps|<=1.5e-7)
__device__ __forceinline__ void gelu3(float u, float &h, float &d, float &e){
  float E   = __expf(-0.5f * u * u);
  float phi = 0.3989422804014327f * E;
  float az  = fabsf(u) * 0.70710678118654752f;
  float t   = __builtin_amdgcn_rcpf(1.0f + 0.3275911f * az);
  float p   = t*(0.254829592f + t*(-0.284496736f + t*(1.421413741f + t*(-1.453152027f + t*1.061405429f))));
  float erfabs = 1.0f - p * E;
  float erfv   = __builtin_copysignf(erfabs, u);
  float Phi = 0.5f * (1.0f + erfv);
  h = u * Phi;
  d = Phi + u * phi;
  e = phi * (2.0f - u * u);
}

// packed-pair exact GELU (v_pk_* f32 path): same constants as gelu3
__device__ __forceinline__ void gelu3x2(f2v u, f2v &h, f2v &d, f2v &e){
  f2v u2 = u * u;
  f2v m  = u2 * (-0.72134752044448170368f);   // -0.5*log2(e)
  f2v E;  E.x = EXP2F(m.x); E.y = EXP2F(m.y);
  f2v phi = 0.3989422804014327f * E;
  f2v az;
  az.x = fabsf(u.x) * 0.70710678118654752f;
  az.y = fabsf(u.y) * 0.70710678118654752f;
  f2v den = 0.3275911f * az + 1.0f;
  f2v t;  t.x = __builtin_amdgcn_rcpf(den.x); t.y = __builtin_amdgcn_rcpf(den.y);
  f2v p = t*(0.254829592f + t*(-0.284496736f + t*(1.421413741f + t*(-1.453152027f + t*1.061405429f))));
  f2v erfabs = 1.0f - p * E;
  f2v erfv;
  erfv.x = __builtin_copysignf(erfabs.x, u.x);
  erfv.y = __builtin_copysignf(erfabs.y, u.y);
  f2v Phi = 0.5f * erfv + 0.5f;
  h = u * Phi;
  d = u * phi + Phi;
  e = phi * (2.0f - u2);
}

// 16-lane row reduction entirely in the VALU pipe (DPP), no LDS ops.
#define DPP_ADD(v, ctrl) { \
  int _si = __builtin_amdgcn_update_dpp(0, __builtin_bit_cast(int, v), ctrl, 0xf, 0xf, true); \
  v += __builtin_bit_cast(float, _si); }

__device__ __forceinline__ float redjb16(float v){
  DPP_ADD(v, 0xB1);
  DPP_ADD(v, 0x4E);
  DPP_ADD(v, 0x124);
  DPP_ADD(v, 0x128);
  return v;
}
// 64-lane reduction: 4 DPP stages within rows + 2 cross-row shuffles
__device__ __forceinline__ float red64(float v){
  v = redjb16(v);
  v += __shfl_xor(v, 16);
  v += __shfl_xor(v, 32);
  return v;
}

__device__ __forceinline__ ushort_t bf16rne(float v){
  union { float f; u32 i; } x; x.f = v;
  u32 r = x.i + 0x7FFFu + ((x.i >> 16) & 1u);
  return (ushort_t)(r >> 16);
}
// packed rne bf16 of two floats -> u32 (low = a, high = b); lowers to v_cvt_pk_bf16_f32
__device__ __forceinline__ u32 pkbf(float a, float b){
  __hip_bfloat162 t = __float22bfloat162_rn(make_float2(a, b));
  u32 r;
  __builtin_memcpy(&r, &t, sizeof(r));
  return r;
}
__device__ __forceinline__ u32 pkbf2(f2v v){
  return pkbf(v.x, v.y);
}

// ---------------- one-time prep: wa/wb + W2 rne-bf16 fragments + lapl-slot zeroing ----------------
__global__ __launch_bounds__(256, 4) void k_pre(
    const float* __restrict__ W1g, const float* __restrict__ W2g,
    float* __restrict__ ws, float* __restrict__ out)
{
  int t = blockIdx.x * 256 + threadIdx.x;     // 0..2047
  if (blockIdx.x == 0 && threadIdx.x < 128) {
    int k = threadIdx.x;
    ws[WA_OFF + k] = W1g[k] + W1g[256+k] + W1g[384+k];
    ws[WB_OFF + k] = W1g[128+k];
  }
  if (blockIdx.x == 1 && threadIdx.x < 64) {
    out[(size_t)threadIdx.x*4097 + 4096] = 0.f;   // lapl accumulators (k_c2 atomicAdds)
  }
  short* BF = (short*)(ws + BF_OFF);
  int w = t >> 9, nt = (t >> 8) & 1, kt = (t >> 6) & 3, lane = t & 63;
  int q = lane >> 4, nlo = lane & 15;
  int n = w*32 + nt*16 + nlo;
  s8v vh;
  #pragma unroll
  for (int jj = 0; jj < 8; ++jj) {
    int k = kt*32 + q*8 + jj;
    vh[jj] = (short)bf16rne(W2g[k*128 + n]);
  }
  *(s8v*)&BF[t*8] = vh;
}

// ---------------- heavy kernel: one (batch, 4-row group), 16 chunks of 16 sites ----------------
// grid 1024 = 64 b * 16 row-groups ; block 256 (4 waves); 3 blocks/CU (LDS dbuf)
// ONE barrier per chunk: wave w's P1 writes only AF kt=w section, so own-kt MFMA
// runs pre-barrier on same-wave data; AF+EP double-buffered; P4 delayed one chunk.
// Streaming B with prefetch (r9 pattern) — NO persistent B registers (rule #20 history).
__global__ __launch_bounds__(256, 3) void k_c1(
    const float* __restrict__ xg, const int* __restrict__ signs,
    const float* __restrict__ b1g, const float* __restrict__ b2g,
    const float* __restrict__ W3g, const float* __restrict__ b3g,
    float* __restrict__ ws)
{
  // AF: [buf][kt(4)][plane(6)] x 512 shorts ; planes: {h, d*wa, d*wb, e*waa, e*wab, e*wbb}
  __shared__ alignas(16) short AF[2][12288];  // 48 KB
  __shared__ float xS[6][64];                 // rows i0-1..i0+4  (1.5 KB)
  __shared__ char  zS[6][64];                 // signs as +-1     (384 B)
  __shared__ float EP[2][16][6][4];           // [buf][site][quant][wave] (3 KB)

  const int tid  = threadIdx.x;
  const int lane = tid & 63;
  const int w    = tid >> 6;
  const int rg4  = (lane >> 4) << 2;          // n-quad base within a 16-n block

  const int blk = blockIdx.x;
  const int b   = blk >> 4;
  const int i0  = (blk & 15) << 2;            // first of four rows

  // per-thread B-fragment pointer (L2-resident pre-rounded W2), streamed with prefetch
  const s8v* BhT = (const s8v*)((const short*)(ws + BF_OFF)) + (w*512 + lane);
  const int ktA = (w + 1) & 3, ktB = (w + 2) & 3, ktC = (w + 3) & 3;

  // per-lane n-quad biases/weights for the transposed epilogue (n = w*32 + nt*16 + rg4 + r)
  float4 b2H[2], w3H[2];
  #pragma unroll
  for (int nt = 0; nt < 2; ++nt) {
    int n0 = w*32 + nt*16 + rg4;
    b2H[nt] = *(const float4*)(b2g + n0);
    w3H[nt] = *(const float4*)(W3g + n0);
  }
  float b3v = b3g[0];

  // P1 thread geometry + loop-invariant layer-1 weights/bias (hoisted)
  const int s_  = tid & 15;
  const int ko_ = tid >> 4;
  float4 waH[2], wbH[2], b1H[2];
  #pragma unroll
  for (int half = 0; half < 2; ++half) {
    int k0 = ko_*8 + half*4;
    waH[half] = *(const float4*)(ws + WA_OFF + k0);
    wbH[half] = *(const float4*)(ws + WB_OFF + k0);
    b1H[half] = *(const float4*)(b1g + k0);
  }

  // ---- stage 6 x-rows and 6 sign-rows ----
  for (int t = tid; t < 384; t += 256) {
    int r = t >> 6, j = t & 63;
    int gr = (i0 - 1 + r) & 63;
    xS[r][j] = xg[(size_t)b*NSITE + gr*64 + j];
    int c = ((gr & 1) << 1) | (j & 1);
    zS[r][j] = (char)(2*signs[((c*NB + b)*LL + gr)*LL + j] - 1);
  }
  __syncthreads();

  float racc[10];
  #pragma unroll
  for (int n = 0; n < 10; ++n) racc[n] = 0.f;

  const f4v Zf = {0.f, 0.f, 0.f, 0.f};        // hoisted zero C-operand
  int lrP = 0, jbP = 0, iP = 0;               // previous-chunk state for delayed P4

  #pragma unroll 1
  for (int ch = 0; ch < 16; ++ch) {
    const int cur = ch & 1;
    const int lr = 1 + (ch >> 2);             // local row 1..4
    const int jb = ch & 3;
    const int i  = i0 + (ch >> 2);

    // ---- own-kt B loads issued early: latency hides under P1 compute ----
    s8v pb0 = BhT[w*64], pb1 = BhT[256 + w*64];

    // ---- P1: build A fragments into AF[cur] (wave w writes only kt=w section) ----
    {
      int j = jb*16 + s_, jm = (j+63)&63, jp = (j+1)&63;
      float p = xS[lr][j];
      float l = xS[lr-1][j] + xS[lr+1][j] + xS[lr][jm] + xS[lr][jp] - 4.0f*p;
      u32 vv[6][4];                           // [plane][half*2+pr]
      #pragma unroll
      for (int half = 0; half < 2; ++half) {
        const float* waA = (const float*)&waH[half];
        const float* wbA = (const float*)&wbH[half];
        const float* b1A = (const float*)&b1H[half];
        #pragma unroll
        for (int pr = 0; pr < 2; ++pr) {
          f2v wa = {waA[pr*2], waA[pr*2+1]};
          f2v wb = {wbA[pr*2], wbA[pr*2+1]};
          f2v bb = {b1A[pr*2], b1A[pr*2+1]};
          f2v u = p*wa + l*wb + bb;
          f2v h, dd, ee;
          gelu3x2(u, h, dd, ee);
          int c = half*2 + pr;
          vv[0][c] = pkbf2(h);
          vv[1][c] = pkbf2(dd*wa);
          vv[2][c] = pkbf2(dd*wb);
          f2v ea = ee*wa, eb = ee*wb;
          vv[3][c] = pkbf2(ea*wa);
          vv[4][c] = pkbf2(ea*wb);
          vv[5][c] = pkbf2(eb*wb);
        }
      }
      // one conflict-free ds_write_b128 per plane (per-wave addr == lane*16 + const)
      short* base = &AF[cur][(ko_>>2)*3072 + ((ko_&3)*16 + s_)*8];
      #pragma unroll
      for (int pp = 0; pp < 6; ++pp)
        *(int4*)&base[pp*512] = make_int4((int)vv[pp][0], (int)vv[pp][1],
                                          (int)vv[pp][2], (int)vv[pp][3]);
    }

    // ---- own-kt MFMA (pre-barrier: reads this wave's own fresh LDS writes) ----
    f4v acc[6][2];
    {
      const short* base = &AF[cur][w*3072 + lane*8];
      #pragma unroll
      for (int pp = 0; pp < 6; ++pp) {
        s8v ah = *(const s8v*)&base[pp*512];
        acc[pp][0] = __builtin_amdgcn_mfma_f32_16x16x32_bf16(pb0, ah, Zf, 0, 0, 0);
        acc[pp][1] = __builtin_amdgcn_mfma_f32_16x16x32_bf16(pb1, ah, Zf, 0, 0, 0);
      }
    }
    // prefetch first other-kt B while waiting at the barrier
    s8v bh0 = BhT[ktA*64], bh1 = BhT[256 + ktA*64];

    __syncthreads();                          // the ONLY barrier per chunk

    // ---- P2-rest: remaining 3 kt sections (cross-wave data now visible) ----
    __builtin_amdgcn_s_setprio(1);
    {
      s8v nh0 = BhT[ktB*64], nh1 = BhT[256 + ktB*64];
      const short* base = &AF[cur][ktA*3072 + lane*8];
      #pragma unroll
      for (int pp = 0; pp < 6; ++pp) {
        s8v ah = *(const s8v*)&base[pp*512];
        acc[pp][0] = __builtin_amdgcn_mfma_f32_16x16x32_bf16(bh0, ah, acc[pp][0], 0, 0, 0);
        acc[pp][1] = __builtin_amdgcn_mfma_f32_16x16x32_bf16(bh1, ah, acc[pp][1], 0, 0, 0);
      }
      bh0 = nh0; bh1 = nh1;
    }
    {
      s8v nh0 = BhT[ktC*64], nh1 = BhT[256 + ktC*64];
      const short* base = &AF[cur][ktB*3072 + lane*8];
      #pragma unroll
      for (int pp = 0; pp < 6; ++pp) {
        s8v ah = *(const s8v*)&base[pp*512];
        acc[pp][0] = __builtin_amdgcn_mfma_f32_16x16x32_bf16(bh0, ah, acc[pp][0], 0, 0, 0);
        acc[pp][1] = __builtin_amdgcn_mfma_f32_16x16x32_bf16(bh1, ah, acc[pp][1], 0, 0, 0);
      }
      bh0 = nh0; bh1 = nh1;
    }
    {
      const short* base = &AF[cur][ktC*3072 + lane*8];
      #pragma unroll
      for (int pp = 0; pp < 6; ++pp) {
        s8v ah = *(const s8v*)&base[pp*512];
        acc[pp][0] = __builtin_amdgcn_mfma_f32_16x16x32_bf16(bh0, ah, acc[pp][0], 0, 0, 0);
        acc[pp][1] = __builtin_amdgcn_mfma_f32_16x16x32_bf16(bh1, ah, acc[pp][1], 0, 0, 0);
      }
    }
    __builtin_amdgcn_s_setprio(0);

    // ---- P3: transposed epilogue — n-sum is per-lane FMA + 2 shfl stages -> EP[cur] ----
    {
      f2v qh = {0.f,0.f}, qA = {0.f,0.f}, qB = {0.f,0.f};
      f2v qa = {0.f,0.f}, qb = {0.f,0.f}, qc = {0.f,0.f};
      #pragma unroll
      for (int nt = 0; nt < 2; ++nt) {
        const float* b2A = (const float*)&b2H[nt];
        const float* w3A = (const float*)&w3H[nt];
        #pragma unroll
        for (int pr = 0; pr < 2; ++pr) {
          const int r0 = pr*2;
          f2v uu  = (f2v){acc[0][nt][r0], acc[0][nt][r0+1]}
                  + (f2v){b2A[r0], b2A[r0+1]};
          f2v w3p = {w3A[r0], w3A[r0+1]};
          f2v h2, d2, e2;
          gelu3x2(uu, h2, d2, e2);
          f2v wd = w3p*d2, we = w3p*e2;
          f2v A  = {acc[1][nt][r0], acc[1][nt][r0+1]};
          f2v Bv = {acc[2][nt][r0], acc[2][nt][r0+1]};
          f2v t3 = {acc[3][nt][r0], acc[3][nt][r0+1]};
          f2v t4 = {acc[4][nt][r0], acc[4][nt][r0+1]};
          f2v t5 = {acc[5][nt][r0], acc[5][nt][r0+1]};
          qh += w3p*h2;
          qA += wd*A;
          qB += wd*Bv;
          qa += we*(A*A)   + wd*t3;
          qb += we*(A*Bv)  + wd*t4;
          qc += we*(Bv*Bv) + wd*t5;
        }
      }
      float sh = qh.x + qh.y;
      float sA = qA.x + qA.y;
      float sB = qB.x + qB.y;
      float sa = qa.x + qa.y;
      float sb = qb.x + qb.y;
      float sc = qc.x + qc.y;
      sh += __shfl_xor(sh, 16); sh += __shfl_xor(sh, 32);
      sA += __shfl_xor(sA, 16); sA += __shfl_xor(sA, 32);
      sB += __shfl_xor(sB, 16); sB += __shfl_xor(sB, 32);
      sa += __shfl_xor(sa, 16); sa += __shfl_xor(sa, 32);
      sb += __shfl_xor(sb, 16); sb += __shfl_xor(sb, 32);
      sc += __shfl_xor(sc, 16); sc += __shfl_xor(sc, 32);
      if (lane < 16) {
        EP[cur][lane][0][w] = sh;
        EP[cur][lane][1][w] = sA;
        EP[cur][lane][2][w] = sB;
        EP[cur][lane][3][w] = sa;
        EP[cur][lane][4][w] = sb;
        EP[cur][lane][5][w] = sc;
      }
    }

    // ---- P4 (delayed one chunk): finalize ch-1 from EP[cur^1]; 16 threads,
    //      overlaps other waves' next-P1 (no barrier until next chunk's sync) ----
    if (ch > 0 && tid < 16) {
      int s = tid;
      float h = 0.f, RA = 0.f, RB = 0.f, TAa = 0.f, TAb = 0.f, TBb = 0.f;
      #pragma unroll
      for (int ww = 0; ww < 4; ++ww) {
        h   += EP[cur^1][s][0][ww];
        RA  += EP[cur^1][s][1][ww];
        RB  += EP[cur^1][s][2][ww];
        TAa += EP[cur^1][s][3][ww];
        TAb += EP[cur^1][s][4][ww];
        TBb += EP[cur^1][s][5][ww];
      }
      h += b3v;
      float* P = ws + PL_OFF;
      int j = jbP*16 + s;
      size_t site = (size_t)b*NSITE + iP*64 + j;
      P[0*BN + site] = h;
      P[1*BN + site] = RA;
      P[2*BN + site] = RB;
      P[3*BN + site] = TAa;
      P[4*BN + site] = TAb;
      P[5*BN + site] = TBb;

      int jm = (j+63)&63, jp = (j+1)&63;
      int c0 = ((iP & 1) << 1) | (j & 1);
      float hd[4] = {0.f, 0.f, 0.f, 0.f};
      hd[c0]     = (float)zS[lrP][j] * (RA - 4.0f*RB);
      hd[c0 ^ 1] = (float)(zS[lrP][jm] + zS[lrP][jp]) * RB;
      hd[c0 ^ 2] = (float)(zS[lrP-1][j] + zS[lrP+1][j]) * RB;
      racc[0] += h;
      racc[1] += h*h;
      #pragma unroll
      for (int cc = 0; cc < 4; ++cc) {
        racc[2+cc] += hd[cc];
        racc[6+cc] += h*hd[cc];
      }
    }

    lrP = lr; jbP = jb; iP = i;
  }

  __syncthreads();

  // ---- final P4 for chunk 15 + block partial write ----
  if (tid < 16) {
    int s = tid;
    float h = 0.f, RA = 0.f, RB = 0.f, TAa = 0.f, TAb = 0.f, TBb = 0.f;
    #pragma unroll
    for (int ww = 0; ww < 4; ++ww) {
      h   += EP[1][s][0][ww];
      RA  += EP[1][s][1][ww];
      RB  += EP[1][s][2][ww];
      TAa += EP[1][s][3][ww];
      TAb += EP[1][s][4][ww];
      TBb += EP[1][s][5][ww];
    }
    h += b3v;
    float* P = ws + PL_OFF;
    int j = jbP*16 + s;
    size_t site = (size_t)b*NSITE + iP*64 + j;
    P[0*BN + site] = h;
    P[1*BN + site] = RA;
    P[2*BN + site] = RB;
    P[3*BN + site] = TAa;
    P[4*BN + site] = TAb;
    P[5*BN + site] = TBb;

    int jm = (j+63)&63, jp = (j+1)&63;
    int c0 = ((iP & 1) << 1) | (j & 1);
    float hd[4] = {0.f, 0.f, 0.f, 0.f};
    hd[c0]     = (float)zS[lrP][j] * (RA - 4.0f*RB);
    hd[c0 ^ 1] = (float)(zS[lrP][jm] + zS[lrP][jp]) * RB;
    hd[c0 ^ 2] = (float)(zS[lrP-1][j] + zS[lrP+1][j]) * RB;
    racc[0] += h;
    racc[1] += h*h;
    #pragma unroll
    for (int cc = 0; cc < 4; ++cc) {
      racc[2+cc] += hd[cc];
      racc[6+cc] += h*hd[cc];
    }

    #pragma unroll
    for (int n = 0; n < 10; ++n) racc[n] = redjb16(racc[n]);
    if (tid == 0) {
      #pragma unroll
      for (int n = 0; n < 10; ++n) ws[RED_OFF + blk*10 + n] = racc[n];
    }
  }
}

// ---------------- stencil + fused head calculus (atomic lapl tail) ----------------
__global__ __launch_bounds__(256, 4) void k_c2(
    const int* __restrict__ signs,
    const float* __restrict__ aW1g, const float* __restrict__ ab1g,
    const float* __restrict__ aW2g,
    float* __restrict__ ws, float* __restrict__ out)
{
  __shared__ float part[4];
  __shared__ float coefL[10];
  __shared__ float redS[10];
  __shared__ float cbS[6][64];
  int blk = blockIdx.x;
  int b = blk >> 4, rg = blk & 15;
  int tid = threadIdx.x;

  // sum the 16 per-block partials for this batch (parallel: 160 threads, DPP rows)
  if (tid < 160) {
    int qq = tid >> 4, g = tid & 15;          // 16-lane DPP row == one quantity
    float v = ws[RED_OFF + (b*16 + g)*10 + qq];
    v = redjb16(v);
    if (g == 0) redS[qq] = v;
  }
  __syncthreads();

  if (tid < 64) {
    int k = tid;
    const float Nf = 4096.0f, Nm1 = 4095.0f;
    float S1 = redS[0], S2 = redS[1];
    float m = S1/Nf, q = S2/Nf;
    float v = (S2 - S1*S1/Nf)/Nm1;
    float w0 = aW1g[k], w1 = aW1g[64+k], w2 = aW1g[128+k];
    float t = m*w0 + v*w1 + q*w2 + ab1g[k];
    float gh, gd, ge;
    gelu3(t, gh, gd, ge);
    float o = aW2g[k];
    float g1o = gd*o, g2o = ge*o;
    float da0 = w0*g1o, da1 = w1*g1o, da2 = w2*g1o;
    float M00 = w0*w0*g2o, M01 = w0*w1*g2o, M02 = w0*w2*g2o;
    float M11 = w1*w1*g2o, M12 = w1*w2*g2o, M22 = w2*w2*g2o;
    da0 = red64(da0); da1 = red64(da1); da2 = red64(da2);
    M00 = red64(M00); M01 = red64(M01); M02 = red64(M02);
    M11 = red64(M11); M12 = red64(M12); M22 = red64(M22);
    if (k == 0) {
      coefL[0] = da0/Nf - 2.0f*da1*m/Nm1;
      coefL[1] = 2.0f*da1/Nm1 + 2.0f*da2/Nf;
      #pragma unroll
      for (int c = 0; c < 4; ++c) {
        float s1 = redS[2 + c], s2 = redS[6 + c];
        float md = s1/Nf, qd = 2.0f*s2/Nf;
        float vd = (2.0f*s2 - 2.0f*S1*s1/Nf)/Nm1;
        float dd0 = M00*md + M01*vd + M02*qd;
        float dd1 = M01*md + M11*vd + M12*qd;
        float dd2 = M02*md + M12*vd + M22*qd;
        coefL[2+c] = dd0/Nf - 2.0f*(dd1*m + da1*md)/Nm1;
        coefL[6+c] = 2.0f*dd1/Nm1 + 2.0f*dd2/Nf;
      }
    }
  }
  __syncthreads();

  const float* P = ws + PL_OFF;
  int base = b*NSITE;
  float alpha = coefL[0], beta = coefL[1];

  // stage cb = (alpha + beta*h) * RB for rows rg*4-1 .. rg*4+4
  for (int t = tid; t < 384; t += 256) {
    int r = t >> 6, jj = t & 63;
    int gr = (rg*4 - 1 + r) & 63;
    int sidx = base + gr*64 + jj;
    cbS[r][jj] = (alpha + beta*P[sidx]) * P[2*BN + sidx];
  }
  __syncthreads();

  int rl = tid >> 6, j = tid & 63;
  int i = rg*4 + rl;
  int im=(i+63)&63, ip=(i+1)&63, jm=(j+63)&63, jp=(j+1)&63;
  int s  = base + i*64 + j;
  float h  = P[s], RA = P[BN+s], RB = P[2*BN+s];
  float TAa= P[3*BN+s], TAb = P[4*BN+s], TBb = P[5*BN+s];
  float g  = alpha + beta*h;
  int lr2 = rl + 1;
  float cb  = cbS[lr2][j];
  float cbu = cbS[lr2-1][j], cbd = cbS[lr2+1][j];
  float cbl = cbS[lr2][jm],  cbr = cbS[lr2][jp];
  float grad = g*RA + (cbu + cbd + cbl + cbr - 4.0f*cb);
  out[(size_t)b*4097 + i*64 + j] = grad;

  int c0 = ((i & 1) << 1) | (j & 1);
  int c1 = c0 ^ 1, c2 = c0 ^ 2;
  float zv = 2.0f*(float)signs[((c0*NB + b)*LL + i )*LL + j ] - 1.0f;
  float zl = 2.0f*(float)signs[((c1*NB + b)*LL + i )*LL + jm] - 1.0f;
  float zr = 2.0f*(float)signs[((c1*NB + b)*LL + i )*LL + jp] - 1.0f;
  float zu = 2.0f*(float)signs[((c2*NB + b)*LL + im)*LL + j ] - 1.0f;
  float zd = 2.0f*(float)signs[((c2*NB + b)*LL + ip)*LL + j ] - 1.0f;
  float sjr = zl + zr, sud = zu + zd;
  float hd0 = zv*(RA - 4.0f*RB);
  float hd1 = sjr*RB, hd2 = sud*RB;
  float gd0 = coefL[2+c0] + coefL[6+c0]*h + beta*hd0;
  float gd1 = coefL[2+c1] + coefL[6+c1]*h + beta*hd1;
  float gd2 = coefL[2+c2] + coefL[6+c2]*h + beta*hd2;
  float ca0 = gd0*RA + g*( zv*TAa - 4.0f*zv*TAb );
  float cb0 = gd0*RB + g*( zv*TAb - 4.0f*zv*TBb );
  float cb1 = gd1*RB + g*( sjr*TBb );
  float cb2 = gd2*RB + g*( sud*TBb );
  float contrib = zv*ca0 - 4.0f*zv*cb0 + sjr*cb1 + sud*cb2;

  float vsum = red64(contrib);
  int wv = tid >> 6;
  if ((tid & 63) == 0) part[wv] = vsum;
  __syncthreads();
  if (tid == 0)
    atomicAdd(out + (size_t)b*4097 + 4096,
              part[0] + part[1] + part[2] + part[3]);
}

extern "C" void kernel_launch(void* const* d_in, const int* in_sizes, int n_in,
                              void* d_out, int out_size, void* d_ws, size_t ws_size,
                              hipStream_t stream) {
  const float* xg    = (const float*)d_in[0];
  const int*   signs = (const int*)d_in[1];
  const float* W1    = (const float*)d_in[2];
  const float* b1    = (const float*)d_in[3];
  const float* W2    = (const float*)d_in[4];
  const float* b2    = (const float*)d_in[5];
  const float* W3    = (const float*)d_in[6];
  const float* b3    = (const float*)d_in[7];
  const float* aW1   = (const float*)d_in[8];
  const float* ab1   = (const float*)d_in[9];
  const float* aW2   = (const float*)d_in[10];
  float* ws  = (float*)d_ws;
  float* out = (float*)d_out;

  hipLaunchKernelGGL(k_pre, dim3(8),    dim3(256), 0, stream, W1, W2, ws, out);
  hipLaunchKernelGGL(k_c1,  dim3(1024), dim3(256), 0, stream,
                     xg, signs, b1, b2, W3, b3, ws);
  hipLaunchKernelGGL(k_c2,  dim3(1024), dim3(256), 0, stream,
                     signs, aW1, ab1, aW2, ws, out);
}

// Round 11
// 180.252 us; speedup vs baseline: 1.0582x; 1.0463x over previous
//
#include <hip/hip_runtime.h>
#include <hip/hip_bf16.h>
#include <math.h>

typedef unsigned short ushort_t;
typedef unsigned int   u32;
typedef __attribute__((ext_vector_type(8))) short s8v;
typedef __attribute__((ext_vector_type(4))) float f4v;
typedef __attribute__((ext_vector_type(2))) float f2v;

#define LL 64
#define NB 64
#define NSITE 4096
#define BN 262144
#define RED_OFF 0         // [0,10240): per-block red partials, blk*10+n
#define WA_OFF  11264
#define WB_OFF  11392
#define PL_OFF  12288     // planes: h, RA, RB, TAa, TAb, TBb (6*BN floats)
#define BF_OFF  (PL_OFF + 6*BN)   // 2048 s8v (bf16-rne W2 fragments)

#if __has_builtin(__builtin_amdgcn_exp2f)
#define EXP2F(x) __builtin_amdgcn_exp2f(x)
#else
#define EXP2F(x) __expf(0.6931471805599453f*(x))
#endif

// fast exact-GELU: value + 1st/2nd derivative. erf via A&S 7.1.26 (|eps|<=1.5e-7)
__device__ __forceinline__ void gelu3(float u, float &h, float &d, float &e){
  float E   = __expf(-0.5f * u * u);
  float phi = 0.3989422804014327f * E;
  float az  = fabsf(u) * 0.70710678118654752f;
  float t   = __builtin_amdgcn_rcpf(1.0f + 0.3275911f * az);
  float p   = t*(0.254829592f + t*(-0.284496736f + t*(1.421413741f + t*(-1.453152027f + t*1.061405429f))));
  float erfabs = 1.0f - p * E;
  float erfv   = __builtin_copysignf(erfabs, u);
  float Phi = 0.5f * (1.0f + erfv);
  h = u * Phi;
  d = Phi + u * phi;
  e = phi * (2.0f - u * u);
}

// packed-pair exact GELU (v_pk_* f32 path): same constants as gelu3
__device__ __forceinline__ void gelu3x2(f2v u, f2v &h, f2v &d, f2v &e){
  f2v u2 = u * u;
  f2v m  = u2 * (-0.72134752044448170368f);   // -0.5*log2(e)
  f2v E;  E.x = EXP2F(m.x); E.y = EXP2F(m.y);
  f2v phi = 0.3989422804014327f * E;
  f2v az;
  az.x = fabsf(u.x) * 0.70710678118654752f;
  az.y = fabsf(u.y) * 0.70710678118654752f;
  f2v den = 0.3275911f * az + 1.0f;
  f2v t;  t.x = __builtin_amdgcn_rcpf(den.x); t.y = __builtin_amdgcn_rcpf(den.y);
  f2v p = t*(0.254829592f + t*(-0.284496736f + t*(1.421413741f + t*(-1.453152027f + t*1.061405429f))));
  f2v erfabs = 1.0f - p * E;
  f2v erfv;
  erfv.x = __builtin_copysignf(erfabs.x, u.x);
  erfv.y = __builtin_copysignf(erfabs.y, u.y);
  f2v Phi = 0.5f * erfv + 0.5f;
  h = u * Phi;
  d = u * phi + Phi;
  e = phi * (2.0f - u2);
}

// 16-lane row reduction entirely in the VALU pipe (DPP), no LDS ops.
#define DPP_ADD(v, ctrl) { \
  int _si = __builtin_amdgcn_update_dpp(0, __builtin_bit_cast(int, v), ctrl, 0xf, 0xf, true); \
  v += __builtin_bit_cast(float, _si); }

__device__ __forceinline__ float redjb16(float v){
  DPP_ADD(v, 0xB1);
  DPP_ADD(v, 0x4E);
  DPP_ADD(v, 0x124);
  DPP_ADD(v, 0x128);
  return v;
}
// 64-lane reduction: 4 DPP stages within rows + 2 cross-row shuffles
__device__ __forceinline__ float red64(float v){
  v = redjb16(v);
  v += __shfl_xor(v, 16);
  v += __shfl_xor(v, 32);
  return v;
}

__device__ __forceinline__ ushort_t bf16rne(float v){
  union { float f; u32 i; } x; x.f = v;
  u32 r = x.i + 0x7FFFu + ((x.i >> 16) & 1u);
  return (ushort_t)(r >> 16);
}
// packed rne bf16 of two floats -> u32 (low = a, high = b); lowers to v_cvt_pk_bf16_f32
__device__ __forceinline__ u32 pkbf(float a, float b){
  __hip_bfloat162 t = __float22bfloat162_rn(make_float2(a, b));
  u32 r;
  __builtin_memcpy(&r, &t, sizeof(r));
  return r;
}
__device__ __forceinline__ u32 pkbf2(f2v v){
  return pkbf(v.x, v.y);
}

// ---------------- one-time prep: wa/wb + W2 rne-bf16 fragments + lapl-slot zeroing ----------------
__global__ __launch_bounds__(256, 4) void k_pre(
    const float* __restrict__ W1g, const float* __restrict__ W2g,
    float* __restrict__ ws, float* __restrict__ out)
{
  int t = blockIdx.x * 256 + threadIdx.x;     // 0..2047
  if (blockIdx.x == 0 && threadIdx.x < 128) {
    int k = threadIdx.x;
    ws[WA_OFF + k] = W1g[k] + W1g[256+k] + W1g[384+k];
    ws[WB_OFF + k] = W1g[128+k];
  }
  if (blockIdx.x == 1 && threadIdx.x < 64) {
    out[(size_t)threadIdx.x*4097 + 4096] = 0.f;   // lapl accumulators (k_c2 atomicAdds)
  }
  short* BF = (short*)(ws + BF_OFF);
  int w = t >> 9, nt = (t >> 8) & 1, kt = (t >> 6) & 3, lane = t & 63;
  int q = lane >> 4, nlo = lane & 15;
  int n = w*32 + nt*16 + nlo;
  s8v vh;
  #pragma unroll
  for (int jj = 0; jj < 8; ++jj) {
    int k = kt*32 + q*8 + jj;
    vh[jj] = (short)bf16rne(W2g[k*128 + n]);
  }
  *(s8v*)&BF[t*8] = vh;
}

// ---------------- heavy kernel: one (batch, 4-row group), 16 chunks of 16 sites ----------------
// grid 1024 = 64 b * 16 row-groups ; block 256 (4 waves); 28 KB LDS -> 4-5 blocks/CU
// r9 structure (2 barriers/chunk, transposed MFMA, pre-P1 B prefetch).
// launch_bounds (256,3): cap ~168 VGPR. At (256,4) the allocator squeezed to 64 and
// SPILLED (r8/r9: +12 MB scratch writes, L2 pollution slowed k_c2). r10 measured the
// same code shape at 80 VGPR with zero spill — this combines r9's structure with that.
__global__ __launch_bounds__(256, 3) void k_c1(
    const float* __restrict__ xg, const int* __restrict__ signs,
    const float* __restrict__ b1g, const float* __restrict__ b2g,
    const float* __restrict__ W3g, const float* __restrict__ b3g,
    float* __restrict__ ws)
{
  // AF: [kt(4)][plane(6)] x 512 shorts ; planes: {h, d*wa, d*wb, e*waa, e*wab, e*wbb}
  __shared__ alignas(16) short AF[12288];     // 24 KB
  __shared__ float xS[6][64];                 // rows i0-1..i0+4  (1.5 KB)
  __shared__ char  zS[6][64];                 // signs as +-1     (384 B)
  __shared__ float EP[16][7][4];              // padded stride (1.75 KB)

  const int tid  = threadIdx.x;
  const int lane = tid & 63;
  const int w    = tid >> 6;
  const int rg4  = (lane >> 4) << 2;          // n-quad base within a 16-n block

  const int blk = blockIdx.x;
  const int b   = blk >> 4;
  const int i0  = (blk & 15) << 2;            // first of four rows

  // per-thread B-fragment pointer (L2-resident pre-rounded W2), streamed with prefetch
  const s8v* BhT = (const s8v*)((const short*)(ws + BF_OFF)) + (w*512 + lane);

  // per-lane n-quad biases/weights for the transposed epilogue (n = w*32 + nt*16 + rg4 + r)
  float4 b2H[2], w3H[2];
  #pragma unroll
  for (int nt = 0; nt < 2; ++nt) {
    int n0 = w*32 + nt*16 + rg4;
    b2H[nt] = *(const float4*)(b2g + n0);
    w3H[nt] = *(const float4*)(W3g + n0);
  }
  float b3v = b3g[0];

  // P1 thread geometry + loop-invariant layer-1 weights/bias (hoisted)
  const int s_  = tid & 15;
  const int ko_ = tid >> 4;
  float4 waH[2], wbH[2], b1H[2];
  #pragma unroll
  for (int half = 0; half < 2; ++half) {
    int k0 = ko_*8 + half*4;
    waH[half] = *(const float4*)(ws + WA_OFF + k0);
    wbH[half] = *(const float4*)(ws + WB_OFF + k0);
    b1H[half] = *(const float4*)(b1g + k0);
  }

  // ---- stage 6 x-rows and 6 sign-rows ----
  for (int t = tid; t < 384; t += 256) {
    int r = t >> 6, j = t & 63;
    int gr = (i0 - 1 + r) & 63;
    xS[r][j] = xg[(size_t)b*NSITE + gr*64 + j];
    int c = ((gr & 1) << 1) | (j & 1);
    zS[r][j] = (char)(2*signs[((c*NB + b)*LL + gr)*LL + j] - 1);
  }
  __syncthreads();

  float racc[10];
  #pragma unroll
  for (int n = 0; n < 10; ++n) racc[n] = 0.f;

  const f4v Zf = {0.f, 0.f, 0.f, 0.f};        // hoisted zero C-operand

  #pragma unroll 1
  for (int ch = 0; ch < 16; ++ch) {
    const int lr = 1 + (ch >> 2);             // local row 1..4
    const int jb = ch & 3;
    const int i  = i0 + (ch >> 2);

    // ---- issue kt0/kt1 B loads early: latency hides under P1 compute ----
    s8v pb00 = BhT[0],  pb10 = BhT[256];
    s8v pb01 = BhT[64], pb11 = BhT[320];

    // ---- P1: build A fragments (packed-pair math, single b128 write per plane) ----
    {
      int j = jb*16 + s_, jm = (j+63)&63, jp = (j+1)&63;
      float p = xS[lr][j];
      float l = xS[lr-1][j] + xS[lr+1][j] + xS[lr][jm] + xS[lr][jp] - 4.0f*p;
      u32 vv[6][4];                           // [plane][half*2+pr]
      #pragma unroll
      for (int half = 0; half < 2; ++half) {
        const float* waA = (const float*)&waH[half];
        const float* wbA = (const float*)&wbH[half];
        const float* b1A = (const float*)&b1H[half];
        #pragma unroll
        for (int pr = 0; pr < 2; ++pr) {
          f2v wa = {waA[pr*2], waA[pr*2+1]};
          f2v wb = {wbA[pr*2], wbA[pr*2+1]};
          f2v bb = {b1A[pr*2], b1A[pr*2+1]};
          f2v u = p*wa + l*wb + bb;
          f2v h, dd, ee;
          gelu3x2(u, h, dd, ee);
          int c = half*2 + pr;
          vv[0][c] = pkbf2(h);
          vv[1][c] = pkbf2(dd*wa);
          vv[2][c] = pkbf2(dd*wb);
          f2v ea = ee*wa, eb = ee*wb;
          vv[3][c] = pkbf2(ea*wa);
          vv[4][c] = pkbf2(ea*wb);
          vv[5][c] = pkbf2(eb*wb);
        }
      }
      // one conflict-free ds_write_b128 per plane (per-wave addr == lane*16 + const)
      short* base = &AF[(ko_>>2)*3072 + ((ko_&3)*16 + s_)*8];
      #pragma unroll
      for (int pp = 0; pp < 6; ++pp)
        *(int4*)&base[pp*512] = make_int4((int)vv[pp][0], (int)vv[pp][1],
                                          (int)vv[pp][2], (int)vv[pp][3]);
    }
    __syncthreads();

    // ---- P2: transposed MFMA (B as a-operand), kt=0 peeled with zero C ----
    f4v acc[6][2];
    __builtin_amdgcn_s_setprio(1);
    {
      const short* base = &AF[lane*8];
      #pragma unroll
      for (int pp = 0; pp < 6; ++pp) {
        s8v ah = *(const s8v*)&base[pp*512];
        acc[pp][0] = __builtin_amdgcn_mfma_f32_16x16x32_bf16(pb00, ah, Zf, 0, 0, 0);
        acc[pp][1] = __builtin_amdgcn_mfma_f32_16x16x32_bf16(pb10, ah, Zf, 0, 0, 0);
      }
    }
    s8v bh0 = pb01, bh1 = pb11;
    #pragma unroll 1
    for (int kt = 1; kt < 4; ++kt) {
      s8v nh0 = bh0, nh1 = bh1;
      if (kt != 3) {
        int o = (kt + 1) * 64;
        nh0 = BhT[o]; nh1 = BhT[256 + o];
      }
      const short* base = &AF[kt*3072 + lane*8];
      #pragma unroll
      for (int pp = 0; pp < 6; ++pp) {
        s8v ah = *(const s8v*)&base[pp*512];
        acc[pp][0] = __builtin_amdgcn_mfma_f32_16x16x32_bf16(bh0, ah, acc[pp][0], 0, 0, 0);
        acc[pp][1] = __builtin_amdgcn_mfma_f32_16x16x32_bf16(bh1, ah, acc[pp][1], 0, 0, 0);
      }
      bh0 = nh0; bh1 = nh1;
    }
    __builtin_amdgcn_s_setprio(0);

    // ---- P3: transposed epilogue — n-sum is per-lane FMA + 2 shfl stages ----
    {
      f2v qh = {0.f,0.f}, qA = {0.f,0.f}, qB = {0.f,0.f};
      f2v qa = {0.f,0.f}, qb = {0.f,0.f}, qc = {0.f,0.f};
      #pragma unroll
      for (int nt = 0; nt < 2; ++nt) {
        const float* b2A = (const float*)&b2H[nt];
        const float* w3A = (const float*)&w3H[nt];
        #pragma unroll
        for (int pr = 0; pr < 2; ++pr) {
          const int r0 = pr*2;
          f2v uu  = (f2v){acc[0][nt][r0], acc[0][nt][r0+1]}
                  + (f2v){b2A[r0], b2A[r0+1]};
          f2v w3p = {w3A[r0], w3A[r0+1]};
          f2v h2, d2, e2;
          gelu3x2(uu, h2, d2, e2);
          f2v wd = w3p*d2, we = w3p*e2;
          f2v A  = {acc[1][nt][r0], acc[1][nt][r0+1]};
          f2v Bv = {acc[2][nt][r0], acc[2][nt][r0+1]};
          f2v t3 = {acc[3][nt][r0], acc[3][nt][r0+1]};
          f2v t4 = {acc[4][nt][r0], acc[4][nt][r0+1]};
          f2v t5 = {acc[5][nt][r0], acc[5][nt][r0+1]};
          qh += w3p*h2;
          qA += wd*A;
          qB += wd*Bv;
          qa += we*(A*A)   + wd*t3;
          qb += we*(A*Bv)  + wd*t4;
          qc += we*(Bv*Bv) + wd*t5;
        }
      }
      float sh = qh.x + qh.y;
      float sA = qA.x + qA.y;
      float sB = qB.x + qB.y;
      float sa = qa.x + qa.y;
      float sb = qb.x + qb.y;
      float sc = qc.x + qc.y;
      sh += __shfl_xor(sh, 16); sh += __shfl_xor(sh, 32);
      sA += __shfl_xor(sA, 16); sA += __shfl_xor(sA, 32);
      sB += __shfl_xor(sB, 16); sB += __shfl_xor(sB, 32);
      sa += __shfl_xor(sa, 16); sa += __shfl_xor(sa, 32);
      sb += __shfl_xor(sb, 16); sb += __shfl_xor(sb, 32);
      sc += __shfl_xor(sc, 16); sc += __shfl_xor(sc, 32);
      if (lane < 16) {
        EP[lane][0][w] = sh;
        EP[lane][1][w] = sA;
        EP[lane][2][w] = sB;
        EP[lane][3][w] = sa;
        EP[lane][4][w] = sb;
        EP[lane][5][w] = sc;
      }
    }
    __syncthreads();

    // ---- P4: per-site finalize + batch accumulation (16 threads; overlaps next P1) ----
    if (tid < 16) {
      int s = tid;
      float h = 0.f, RA = 0.f, RB = 0.f, TAa = 0.f, TAb = 0.f, TBb = 0.f;
      #pragma unroll
      for (int ww = 0; ww < 4; ++ww) {
        h   += EP[s][0][ww];
        RA  += EP[s][1][ww];
        RB  += EP[s][2][ww];
        TAa += EP[s][3][ww];
        TAb += EP[s][4][ww];
        TBb += EP[s][5][ww];
      }
      h += b3v;
      float* P = ws + PL_OFF;
      int j = jb*16 + s;
      size_t site = (size_t)b*NSITE + i*64 + j;
      P[0*BN + site] = h;
      P[1*BN + site] = RA;
      P[2*BN + site] = RB;
      P[3*BN + site] = TAa;
      P[4*BN + site] = TAb;
      P[5*BN + site] = TBb;

      int jm = (j+63)&63, jp = (j+1)&63;
      int c0 = ((i & 1) << 1) | (j & 1);
      float hd[4] = {0.f, 0.f, 0.f, 0.f};
      hd[c0]     = (float)zS[lr][j] * (RA - 4.0f*RB);
      hd[c0 ^ 1] = (float)(zS[lr][jm] + zS[lr][jp]) * RB;
      hd[c0 ^ 2] = (float)(zS[lr-1][j] + zS[lr+1][j]) * RB;
      racc[0] += h;
      racc[1] += h*h;
      #pragma unroll
      for (int cc = 0; cc < 4; ++cc) {
        racc[2+cc] += hd[cc];
        racc[6+cc] += h*hd[cc];
      }
    }
  }

  // ---- final batch reduction: write this block's partials to its private slot ----
  if (tid < 16) {
    #pragma unroll
    for (int n = 0; n < 10; ++n) racc[n] = redjb16(racc[n]);
    if (tid == 0) {
      #pragma unroll
      for (int n = 0; n < 10; ++n) ws[RED_OFF + blk*10 + n] = racc[n];
    }
  }
}

// ---------------- stencil + fused head calculus (atomic lapl tail) ----------------
__global__ __launch_bounds__(256, 4) void k_c2(
    const int* __restrict__ signs,
    const float* __restrict__ aW1g, const float* __restrict__ ab1g,
    const float* __restrict__ aW2g,
    float* __restrict__ ws, float* __restrict__ out)
{
  __shared__ float part[4];
  __shared__ float coefL[10];
  __shared__ float redS[10];
  __shared__ float cbS[6][64];
  int blk = blockIdx.x;
  int b = blk >> 4, rg = blk & 15;
  int tid = threadIdx.x;

  // sum the 16 per-block partials for this batch (parallel: 160 threads, DPP rows)
  if (tid < 160) {
    int qq = tid >> 4, g = tid & 15;          // 16-lane DPP row == one quantity
    float v = ws[RED_OFF + (b*16 + g)*10 + qq];
    v = redjb16(v);
    if (g == 0) redS[qq] = v;
  }
  __syncthreads();

  if (tid < 64) {
    int k = tid;
    const float Nf = 4096.0f, Nm1 = 4095.0f;
    float S1 = redS[0], S2 = redS[1];
    float m = S1/Nf, q = S2/Nf;
    float v = (S2 - S1*S1/Nf)/Nm1;
    float w0 = aW1g[k], w1 = aW1g[64+k], w2 = aW1g[128+k];
    float t = m*w0 + v*w1 + q*w2 + ab1g[k];
    float gh, gd, ge;
    gelu3(t, gh, gd, ge);
    float o = aW2g[k];
    float g1o = gd*o, g2o = ge*o;
    float da0 = w0*g1o, da1 = w1*g1o, da2 = w2*g1o;
    float M00 = w0*w0*g2o, M01 = w0*w1*g2o, M02 = w0*w2*g2o;
    float M11 = w1*w1*g2o, M12 = w1*w2*g2o, M22 = w2*w2*g2o;
    da0 = red64(da0); da1 = red64(da1); da2 = red64(da2);
    M00 = red64(M00); M01 = red64(M01); M02 = red64(M02);
    M11 = red64(M11); M12 = red64(M12); M22 = red64(M22);
    if (k == 0) {
      coefL[0] = da0/Nf - 2.0f*da1*m/Nm1;
      coefL[1] = 2.0f*da1/Nm1 + 2.0f*da2/Nf;
      #pragma unroll
      for (int c = 0; c < 4; ++c) {
        float s1 = redS[2 + c], s2 = redS[6 + c];
        float md = s1/Nf, qd = 2.0f*s2/Nf;
        float vd = (2.0f*s2 - 2.0f*S1*s1/Nf)/Nm1;
        float dd0 = M00*md + M01*vd + M02*qd;
        float dd1 = M01*md + M11*vd + M12*qd;
        float dd2 = M02*md + M12*vd + M22*qd;
        coefL[2+c] = dd0/Nf - 2.0f*(dd1*m + da1*md)/Nm1;
        coefL[6+c] = 2.0f*dd1/Nm1 + 2.0f*dd2/Nf;
      }
    }
  }
  __syncthreads();

  const float* P = ws + PL_OFF;
  int base = b*NSITE;
  float alpha = coefL[0], beta = coefL[1];

  // stage cb = (alpha + beta*h) * RB for rows rg*4-1 .. rg*4+4
  for (int t = tid; t < 384; t += 256) {
    int r = t >> 6, jj = t & 63;
    int gr = (rg*4 - 1 + r) & 63;
    int sidx = base + gr*64 + jj;
    cbS[r][jj] = (alpha + beta*P[sidx]) * P[2*BN + sidx];
  }
  __syncthreads();

  int rl = tid >> 6, j = tid & 63;
  int i = rg*4 + rl;
  int im=(i+63)&63, ip=(i+1)&63, jm=(j+63)&63, jp=(j+1)&63;
  int s  = base + i*64 + j;
  float h  = P[s], RA = P[BN+s], RB = P[2*BN+s];
  float TAa= P[3*BN+s], TAb = P[4*BN+s], TBb = P[5*BN+s];
  float g  = alpha + beta*h;
  int lr2 = rl + 1;
  float cb  = cbS[lr2][j];
  float cbu = cbS[lr2-1][j], cbd = cbS[lr2+1][j];
  float cbl = cbS[lr2][jm],  cbr = cbS[lr2][jp];
  float grad = g*RA + (cbu + cbd + cbl + cbr - 4.0f*cb);
  out[(size_t)b*4097 + i*64 + j] = grad;

  int c0 = ((i & 1) << 1) | (j & 1);
  int c1 = c0 ^ 1, c2 = c0 ^ 2;
  float zv = 2.0f*(float)signs[((c0*NB + b)*LL + i )*LL + j ] - 1.0f;
  float zl = 2.0f*(float)signs[((c1*NB + b)*LL + i )*LL + jm] - 1.0f;
  float zr = 2.0f*(float)signs[((c1*NB + b)*LL + i )*LL + jp] - 1.0f;
  float zu = 2.0f*(float)signs[((c2*NB + b)*LL + im)*LL + j ] - 1.0f;
  float zd = 2.0f*(float)signs[((c2*NB + b)*LL + ip)*LL + j ] - 1.0f;
  float sjr = zl + zr, sud = zu + zd;
  float hd0 = zv*(RA - 4.0f*RB);
  float hd1 = sjr*RB, hd2 = sud*RB;
  float gd0 = coefL[2+c0] + coefL[6+c0]*h + beta*hd0;
  float gd1 = coefL[2+c1] + coefL[6+c1]*h + beta*hd1;
  float gd2 = coefL[2+c2] + coefL[6+c2]*h + beta*hd2;
  float ca0 = gd0*RA + g*( zv*TAa - 4.0f*zv*TAb );
  float cb0 = gd0*RB + g*( zv*TAb - 4.0f*zv*TBb );
  float cb1 = gd1*RB + g*( sjr*TBb );
  float cb2 = gd2*RB + g*( sud*TBb );
  float contrib = zv*ca0 - 4.0f*zv*cb0 + sjr*cb1 + sud*cb2;

  float vsum = red64(contrib);
  int wv = tid >> 6;
  if ((tid & 63) == 0) part[wv] = vsum;
  __syncthreads();
  if (tid == 0)
    atomicAdd(out + (size_t)b*4097 + 4096,
              part[0] + part[1] + part[2] + part[3]);
}

extern "C" void kernel_launch(void* const* d_in, const int* in_sizes, int n_in,
                              void* d_out, int out_size, void* d_ws, size_t ws_size,
                              hipStream_t stream) {
  const float* xg    = (const float*)d_in[0];
  const int*   signs = (const int*)d_in[1];
  const float* W1    = (const float*)d_in[2];
  const float* b1    = (const float*)d_in[3];
  const float* W2    = (const float*)d_in[4];
  const float* b2    = (const float*)d_in[5];
  const float* W3    = (const float*)d_in[6];
  const float* b3    = (const float*)d_in[7];
  const float* aW1   = (const float*)d_in[8];
  const float* ab1   = (const float*)d_in[9];
  const float* aW2   = (const float*)d_in[10];
  float* ws  = (float*)d_ws;
  float* out = (float*)d_out;

  hipLaunchKernelGGL(k_pre, dim3(8),    dim3(256), 0, stream, W1, W2, ws, out);
  hipLaunchKernelGGL(k_c1,  dim3(1024), dim3(256), 0, stream,
                     xg, signs, b1, b2, W3, b3, ws);
  hipLaunchKernelGGL(k_c2,  dim3(1024), dim3(256), 0, stream,
                     signs, aW1, ab1, aW2, ws, out);
}